// Round 1
// baseline (1115.077 us; speedup 1.0000x reference)
//
#include <hip/hip_runtime.h>

#define MODEL_D 128
#define NPB 8  // nodes per block in MLP kernel

// ---------------------------------------------------------------------------
// Scatter-add: agg[dst[e]][:] += feat[src[e]][:]
// 32 lanes per edge; each lane gathers a float4 and does 4 atomic adds.
// ---------------------------------------------------------------------------
__global__ __launch_bounds__(256) void scatter_add_kernel(
    const float* __restrict__ feat,
    const int* __restrict__ src,
    const int* __restrict__ dst,
    float* __restrict__ agg,
    int E)
{
    int gid = blockIdx.x * 256 + threadIdx.x;
    int e = gid >> 5;
    if (e >= E) return;
    int off = (gid & 31) << 2;  // float offset within row: 0,4,...,124
    int s = src[e];
    int d = dst[e];
    float4 v = *reinterpret_cast<const float4*>(feat + (size_t)s * MODEL_D + off);
    float* p = agg + (size_t)d * MODEL_D + off;
    atomicAdd(p + 0, v.x);
    atomicAdd(p + 1, v.y);
    atomicAdd(p + 2, v.z);
    atomicAdd(p + 3, v.w);
}

// ---------------------------------------------------------------------------
// Fused 3-layer MLP: out = relu(relu([agg|feat] @ W1 + b1) @ W2 + b2) @ W3 + b3
// 128 threads/block, thread j owns output column j; 8 nodes per block.
// Activations staged in LDS (broadcast reads), weights streamed from L2
// (coalesced), 8-node reuse per weight load.
// ---------------------------------------------------------------------------
__global__ __launch_bounds__(128) void mlp_kernel(
    const float* __restrict__ agg,
    const float* __restrict__ feat,
    const float* __restrict__ W1, const float* __restrict__ b1,
    const float* __restrict__ W2, const float* __restrict__ b2,
    const float* __restrict__ W3, const float* __restrict__ b3,
    float* __restrict__ out,
    int N)
{
    __shared__ float xs[NPB][2 * MODEL_D];  // 8 KB: concat(agg, feat), later h2
    __shared__ float hs[NPB][MODEL_D];      // 4 KB: h1

    const int j = threadIdx.x;       // 0..127 output column
    const int n0 = blockIdx.x * NPB;

    // Stage x = [agg | feat] for NPB nodes (coalesced)
    #pragma unroll
    for (int n = 0; n < NPB; ++n) {
        int node = n0 + n;
        float a = 0.f, f = 0.f;
        if (node < N) {
            a = agg[(size_t)node * MODEL_D + j];
            f = feat[(size_t)node * MODEL_D + j];
        }
        xs[n][j] = a;
        xs[n][MODEL_D + j] = f;
    }
    __syncthreads();

    float acc[NPB];

    // ---- layer 1: [2D] -> [D], ReLU ----
    {
        float bias = b1[j];
        #pragma unroll
        for (int n = 0; n < NPB; ++n) acc[n] = bias;
        for (int k = 0; k < 2 * MODEL_D; k += 4) {
            float w0 = W1[(k + 0) * MODEL_D + j];
            float w1 = W1[(k + 1) * MODEL_D + j];
            float w2 = W1[(k + 2) * MODEL_D + j];
            float w3 = W1[(k + 3) * MODEL_D + j];
            #pragma unroll
            for (int n = 0; n < NPB; ++n) {
                float4 x = *reinterpret_cast<const float4*>(&xs[n][k]);
                acc[n] = fmaf(x.x, w0, acc[n]);
                acc[n] = fmaf(x.y, w1, acc[n]);
                acc[n] = fmaf(x.z, w2, acc[n]);
                acc[n] = fmaf(x.w, w3, acc[n]);
            }
        }
        #pragma unroll
        for (int n = 0; n < NPB; ++n) hs[n][j] = fmaxf(acc[n], 0.f);
    }
    __syncthreads();

    // ---- layer 2: [D] -> [D], ReLU ----
    {
        float bias = b2[j];
        #pragma unroll
        for (int n = 0; n < NPB; ++n) acc[n] = bias;
        for (int k = 0; k < MODEL_D; k += 4) {
            float w0 = W2[(k + 0) * MODEL_D + j];
            float w1 = W2[(k + 1) * MODEL_D + j];
            float w2 = W2[(k + 2) * MODEL_D + j];
            float w3 = W2[(k + 3) * MODEL_D + j];
            #pragma unroll
            for (int n = 0; n < NPB; ++n) {
                float4 x = *reinterpret_cast<const float4*>(&hs[n][k]);
                acc[n] = fmaf(x.x, w0, acc[n]);
                acc[n] = fmaf(x.y, w1, acc[n]);
                acc[n] = fmaf(x.z, w2, acc[n]);
                acc[n] = fmaf(x.w, w3, acc[n]);
            }
        }
        // h2 written into xs (xs no longer read)
        #pragma unroll
        for (int n = 0; n < NPB; ++n) xs[n][j] = fmaxf(acc[n], 0.f);
    }
    __syncthreads();

    // ---- layer 3: [D] -> [D], no activation ----
    {
        float bias = b3[j];
        #pragma unroll
        for (int n = 0; n < NPB; ++n) acc[n] = bias;
        for (int k = 0; k < MODEL_D; k += 4) {
            float w0 = W3[(k + 0) * MODEL_D + j];
            float w1 = W3[(k + 1) * MODEL_D + j];
            float w2 = W3[(k + 2) * MODEL_D + j];
            float w3 = W3[(k + 3) * MODEL_D + j];
            #pragma unroll
            for (int n = 0; n < NPB; ++n) {
                float4 x = *reinterpret_cast<const float4*>(&xs[n][k]);
                acc[n] = fmaf(x.x, w0, acc[n]);
                acc[n] = fmaf(x.y, w1, acc[n]);
                acc[n] = fmaf(x.z, w2, acc[n]);
                acc[n] = fmaf(x.w, w3, acc[n]);
            }
        }
        #pragma unroll
        for (int n = 0; n < NPB; ++n) {
            int node = n0 + n;
            if (node < N) out[(size_t)node * MODEL_D + j] = acc[n];
        }
    }
}

extern "C" void kernel_launch(void* const* d_in, const int* in_sizes, int n_in,
                              void* d_out, int out_size, void* d_ws, size_t ws_size,
                              hipStream_t stream) {
    const float* feat = (const float*)d_in[0];
    const int*   src  = (const int*)d_in[1];
    const int*   dst  = (const int*)d_in[2];
    const float* W1   = (const float*)d_in[3];
    const float* b1   = (const float*)d_in[4];
    const float* W2   = (const float*)d_in[5];
    const float* b2   = (const float*)d_in[6];
    const float* W3   = (const float*)d_in[7];
    const float* b3   = (const float*)d_in[8];
    float* out = (float*)d_out;

    const int N = in_sizes[0] / MODEL_D;
    const int E = in_sizes[1];

    float* agg = (float*)d_ws;
    size_t aggBytes = (size_t)N * MODEL_D * sizeof(float);
    hipMemsetAsync(agg, 0, aggBytes, stream);

    // scatter: 32 lanes per edge
    long long threads = (long long)E * 32;
    int sblocks = (int)((threads + 255) / 256);
    scatter_add_kernel<<<sblocks, 256, 0, stream>>>(feat, src, dst, agg, E);

    int mblocks = (N + NPB - 1) / NPB;
    mlp_kernel<<<mblocks, 128, 0, stream>>>(agg, feat, W1, b1, W2, b2, W3, b3, out, N);
}

// Round 2
// 188.073 us; speedup vs baseline: 5.9290x; 5.9290x over previous
//
#include <hip/hip_runtime.h>

#define MODEL_D 128
#define NPB 8  // nodes per block in fused kernel

// ---------------------------------------------------------------------------
// Step 1: histogram of dst -> deg[]
// ---------------------------------------------------------------------------
__global__ __launch_bounds__(256) void hist_kernel(
    const int* __restrict__ dst, int* __restrict__ deg, int E)
{
    int i = blockIdx.x * 256 + threadIdx.x;
    int stride = gridDim.x * 256;
    for (; i < E; i += stride) atomicAdd(&deg[dst[i]], 1);
}

// ---------------------------------------------------------------------------
// Step 2: exclusive scan of deg -> offsets, cursor (single block, 1024 thr)
// ---------------------------------------------------------------------------
__global__ __launch_bounds__(1024) void scan_kernel(
    const int* __restrict__ deg, int* __restrict__ offsets,
    int* __restrict__ cursor, int N)
{
    __shared__ int sums[1024];
    int t = threadIdx.x;
    int chunk = (N + 1023) >> 10;
    int start = t * chunk;
    int end = min(start + chunk, N);
    int s = 0;
    for (int i = start; i < end; ++i) s += deg[i];
    sums[t] = s;
    __syncthreads();
    // Hillis-Steele inclusive scan over 1024 partials
    for (int d = 1; d < 1024; d <<= 1) {
        int v = (t >= d) ? sums[t - d] : 0;
        __syncthreads();
        sums[t] += v;
        __syncthreads();
    }
    int pre = (t == 0) ? 0 : sums[t - 1];
    for (int i = start; i < end; ++i) {
        offsets[i] = pre;
        cursor[i] = pre;
        pre += deg[i];
    }
}

// ---------------------------------------------------------------------------
// Step 3: bucket fill -> srcSorted[] grouped by dst
// ---------------------------------------------------------------------------
__global__ __launch_bounds__(256) void fill_kernel(
    const int* __restrict__ src, const int* __restrict__ dst,
    int* __restrict__ cursor, int* __restrict__ srcSorted, int E)
{
    int i = blockIdx.x * 256 + threadIdx.x;
    int stride = gridDim.x * 256;
    for (; i < E; i += stride) {
        int pos = atomicAdd(&cursor[dst[i]], 1);
        srcSorted[pos] = src[i];
    }
}

// ---------------------------------------------------------------------------
// Step 4: fused CSR-aggregate + 3-layer MLP.
// 128 threads/block, thread j owns column j; NPB nodes per block.
// Aggregation: per node, loop its CSR bucket; each iteration is a uniform
// index load (scalar path) + a fully-coalesced 512B row read (L2-resident
// feat) accumulated in a register. Then concat(agg, feat) -> LDS -> MLP.
// ---------------------------------------------------------------------------
__global__ __launch_bounds__(128) void fused_agg_mlp_kernel(
    const float* __restrict__ feat,
    const int* __restrict__ offsets, const int* __restrict__ deg,
    const int* __restrict__ srcSorted,
    const float* __restrict__ W1, const float* __restrict__ b1,
    const float* __restrict__ W2, const float* __restrict__ b2,
    const float* __restrict__ W3, const float* __restrict__ b3,
    float* __restrict__ out,
    int N)
{
    __shared__ float xs[NPB][2 * MODEL_D];  // 8 KB: concat(agg, feat), later h2
    __shared__ float hs[NPB][MODEL_D];      // 4 KB: h1

    const int j = threadIdx.x;       // 0..127 output column
    const int n0 = blockIdx.x * NPB;

    // ---- aggregation phase ----
    for (int n = 0; n < NPB; ++n) {
        int node = n0 + n;
        float a = 0.f, f = 0.f;
        if (node < N) {
            f = feat[(size_t)node * MODEL_D + j];
            int beg = offsets[node];
            int cnt = deg[node];
            int i = 0;
            for (; i + 4 <= cnt; i += 4) {
                int s0 = srcSorted[beg + i + 0];
                int s1 = srcSorted[beg + i + 1];
                int s2 = srcSorted[beg + i + 2];
                int s3 = srcSorted[beg + i + 3];
                float f0 = feat[(size_t)s0 * MODEL_D + j];
                float f1 = feat[(size_t)s1 * MODEL_D + j];
                float f2 = feat[(size_t)s2 * MODEL_D + j];
                float f3 = feat[(size_t)s3 * MODEL_D + j];
                a += f0 + f1 + f2 + f3;
            }
            for (; i < cnt; ++i)
                a += feat[(size_t)srcSorted[beg + i] * MODEL_D + j];
        }
        xs[n][j] = a;
        xs[n][MODEL_D + j] = f;
    }
    __syncthreads();

    float acc[NPB];

    // ---- layer 1: [2D] -> [D], ReLU ----
    {
        float bias = b1[j];
        #pragma unroll
        for (int n = 0; n < NPB; ++n) acc[n] = bias;
        for (int k = 0; k < 2 * MODEL_D; k += 4) {
            float w0 = W1[(k + 0) * MODEL_D + j];
            float w1 = W1[(k + 1) * MODEL_D + j];
            float w2 = W1[(k + 2) * MODEL_D + j];
            float w3 = W1[(k + 3) * MODEL_D + j];
            #pragma unroll
            for (int n = 0; n < NPB; ++n) {
                float4 x = *reinterpret_cast<const float4*>(&xs[n][k]);
                acc[n] = fmaf(x.x, w0, acc[n]);
                acc[n] = fmaf(x.y, w1, acc[n]);
                acc[n] = fmaf(x.z, w2, acc[n]);
                acc[n] = fmaf(x.w, w3, acc[n]);
            }
        }
        #pragma unroll
        for (int n = 0; n < NPB; ++n) hs[n][j] = fmaxf(acc[n], 0.f);
    }
    __syncthreads();

    // ---- layer 2: [D] -> [D], ReLU ----
    {
        float bias = b2[j];
        #pragma unroll
        for (int n = 0; n < NPB; ++n) acc[n] = bias;
        for (int k = 0; k < MODEL_D; k += 4) {
            float w0 = W2[(k + 0) * MODEL_D + j];
            float w1 = W2[(k + 1) * MODEL_D + j];
            float w2 = W2[(k + 2) * MODEL_D + j];
            float w3 = W2[(k + 3) * MODEL_D + j];
            #pragma unroll
            for (int n = 0; n < NPB; ++n) {
                float4 x = *reinterpret_cast<const float4*>(&hs[n][k]);
                acc[n] = fmaf(x.x, w0, acc[n]);
                acc[n] = fmaf(x.y, w1, acc[n]);
                acc[n] = fmaf(x.z, w2, acc[n]);
                acc[n] = fmaf(x.w, w3, acc[n]);
            }
        }
        __syncthreads();  // xs still read above? no — hs read; but xs rewrite below needs all layer-1 reads of xs done (they are, before first barrier). This barrier orders hs reads vs xs writes? hs reads happen in this block; keep write after reads via accumulation order below.
        #pragma unroll
        for (int n = 0; n < NPB; ++n) xs[n][j] = fmaxf(acc[n], 0.f);
    }
    __syncthreads();

    // ---- layer 3: [D] -> [D], no activation ----
    {
        float bias = b3[j];
        #pragma unroll
        for (int n = 0; n < NPB; ++n) acc[n] = bias;
        for (int k = 0; k < MODEL_D; k += 4) {
            float w0 = W3[(k + 0) * MODEL_D + j];
            float w1 = W3[(k + 1) * MODEL_D + j];
            float w2 = W3[(k + 2) * MODEL_D + j];
            float w3 = W3[(k + 3) * MODEL_D + j];
            #pragma unroll
            for (int n = 0; n < NPB; ++n) {
                float4 x = *reinterpret_cast<const float4*>(&xs[n][k]);
                acc[n] = fmaf(x.x, w0, acc[n]);
                acc[n] = fmaf(x.y, w1, acc[n]);
                acc[n] = fmaf(x.z, w2, acc[n]);
                acc[n] = fmaf(x.w, w3, acc[n]);
            }
        }
        #pragma unroll
        for (int n = 0; n < NPB; ++n) {
            int node = n0 + n;
            if (node < N) out[(size_t)node * MODEL_D + j] = acc[n];
        }
    }
}

extern "C" void kernel_launch(void* const* d_in, const int* in_sizes, int n_in,
                              void* d_out, int out_size, void* d_ws, size_t ws_size,
                              hipStream_t stream) {
    const float* feat = (const float*)d_in[0];
    const int*   src  = (const int*)d_in[1];
    const int*   dst  = (const int*)d_in[2];
    const float* W1   = (const float*)d_in[3];
    const float* b1   = (const float*)d_in[4];
    const float* W2   = (const float*)d_in[5];
    const float* b2   = (const float*)d_in[6];
    const float* W3   = (const float*)d_in[7];
    const float* b3   = (const float*)d_in[8];
    float* out = (float*)d_out;

    const int N = in_sizes[0] / MODEL_D;
    const int E = in_sizes[1];

    // workspace layout (ints): deg[N] | offsets[N] | cursor[N] | srcSorted[E]
    int* deg       = (int*)d_ws;
    int* offsets   = deg + N;
    int* cursor    = offsets + N;
    int* srcSorted = cursor + N;

    hipMemsetAsync(deg, 0, (size_t)N * sizeof(int), stream);

    int gE = min((E + 255) / 256, 2048);
    hist_kernel<<<gE, 256, 0, stream>>>(dst, deg, E);
    scan_kernel<<<1, 1024, 0, stream>>>(deg, offsets, cursor, N);
    fill_kernel<<<gE, 256, 0, stream>>>(src, dst, cursor, srcSorted, E);

    int mblocks = (N + NPB - 1) / NPB;
    fused_agg_mlp_kernel<<<mblocks, 128, 0, stream>>>(
        feat, offsets, deg, srcSorted, W1, b1, W2, b2, W3, b3, out, N);
}

// Round 3
// 171.319 us; speedup vs baseline: 6.5088x; 1.0978x over previous
//
#include <hip/hip_runtime.h>

#define MODEL_D 128
#define NPB 16      // nodes per block in MLP kernel
#define MLP_THREADS 256

// ---------------------------------------------------------------------------
// Step 1: histogram of dst -> deg[]
// ---------------------------------------------------------------------------
__global__ __launch_bounds__(1024) void hist_kernel(
    const int* __restrict__ dst, int* __restrict__ deg, int E)
{
    int i = blockIdx.x * 1024 + threadIdx.x;
    int stride = gridDim.x * 1024;
    for (; i < E; i += stride) atomicAdd(&deg[dst[i]], 1);
}

// ---------------------------------------------------------------------------
// Step 2: exclusive scan of deg -> offsets, cursor (single block, 1024 thr)
// ---------------------------------------------------------------------------
__global__ __launch_bounds__(1024) void scan_kernel(
    const int* __restrict__ deg, int* __restrict__ offsets,
    int* __restrict__ cursor, int N)
{
    __shared__ int sums[1024];
    int t = threadIdx.x;
    int chunk = (N + 1023) >> 10;
    int start = t * chunk;
    int end = min(start + chunk, N);
    int s = 0;
    for (int i = start; i < end; ++i) s += deg[i];
    sums[t] = s;
    __syncthreads();
    for (int d = 1; d < 1024; d <<= 1) {
        int v = (t >= d) ? sums[t - d] : 0;
        __syncthreads();
        sums[t] += v;
        __syncthreads();
    }
    int pre = (t == 0) ? 0 : sums[t - 1];
    for (int i = start; i < end; ++i) {
        offsets[i] = pre;
        cursor[i] = pre;
        pre += deg[i];
    }
}

// ---------------------------------------------------------------------------
// Step 3: bucket fill -> srcSorted[] grouped by dst
// ---------------------------------------------------------------------------
__global__ __launch_bounds__(1024) void fill_kernel(
    const int* __restrict__ src, const int* __restrict__ dst,
    int* __restrict__ cursor, int* __restrict__ srcSorted, int E)
{
    int i = blockIdx.x * 1024 + threadIdx.x;
    int stride = gridDim.x * 1024;
    for (; i < E; i += stride) {
        int pos = atomicAdd(&cursor[dst[i]], 1);
        srcSorted[pos] = src[i];
    }
}

// ---------------------------------------------------------------------------
// Step 4: CSR aggregation, one thread per (node, column).
// 5000 blocks x 256 threads = full occupancy; unroll-8 gathers for MLP
// latency hiding. feat is 5 MB -> L2/L3 resident; gathers are coalesced
// 512B row reads across the node's 128 threads.
// ---------------------------------------------------------------------------
__global__ __launch_bounds__(256) void agg_kernel(
    const float* __restrict__ feat,
    const int* __restrict__ offsets, const int* __restrict__ deg,
    const int* __restrict__ srcSorted,
    float* __restrict__ agg, int N)
{
    int gid = blockIdx.x * 256 + threadIdx.x;
    int node = gid >> 7;
    if (node >= N) return;
    int j = gid & (MODEL_D - 1);

    int beg = offsets[node];
    int cnt = deg[node];
    float a = 0.f;
    int i = 0;
    for (; i + 8 <= cnt; i += 8) {
        int s0 = srcSorted[beg + i + 0];
        int s1 = srcSorted[beg + i + 1];
        int s2 = srcSorted[beg + i + 2];
        int s3 = srcSorted[beg + i + 3];
        int s4 = srcSorted[beg + i + 4];
        int s5 = srcSorted[beg + i + 5];
        int s6 = srcSorted[beg + i + 6];
        int s7 = srcSorted[beg + i + 7];
        float f0 = feat[(size_t)s0 * MODEL_D + j];
        float f1 = feat[(size_t)s1 * MODEL_D + j];
        float f2 = feat[(size_t)s2 * MODEL_D + j];
        float f3 = feat[(size_t)s3 * MODEL_D + j];
        float f4 = feat[(size_t)s4 * MODEL_D + j];
        float f5 = feat[(size_t)s5 * MODEL_D + j];
        float f6 = feat[(size_t)s6 * MODEL_D + j];
        float f7 = feat[(size_t)s7 * MODEL_D + j];
        a += ((f0 + f1) + (f2 + f3)) + ((f4 + f5) + (f6 + f7));
    }
    for (; i < cnt; ++i)
        a += feat[(size_t)srcSorted[beg + i] * MODEL_D + j];
    agg[(size_t)node * MODEL_D + j] = a;
}

// ---------------------------------------------------------------------------
// Step 5: 3-layer MLP. 256 threads/block, 16 nodes/block (625 blocks).
// Thread (g = t>>7, j = t&127) computes output column j for nodes
// [g*8, g*8+8) of the block's 16. Activations in LDS (broadcast reads),
// weights streamed from L2 with 16-node reuse.
// ---------------------------------------------------------------------------
__global__ __launch_bounds__(MLP_THREADS) void mlp_kernel(
    const float* __restrict__ agg,
    const float* __restrict__ feat,
    const float* __restrict__ W1, const float* __restrict__ b1,
    const float* __restrict__ W2, const float* __restrict__ b2,
    const float* __restrict__ W3, const float* __restrict__ b3,
    float* __restrict__ out,
    int N)
{
    __shared__ float xs[NPB][2 * MODEL_D];  // 16 KB
    __shared__ float hs[NPB][MODEL_D];      // 8 KB

    const int t = threadIdx.x;
    const int j = t & (MODEL_D - 1);
    const int g = t >> 7;          // 0..1
    const int n0 = blockIdx.x * NPB;

    // Stage x = [agg | feat] for NPB nodes; each half-block stages 8 nodes.
    #pragma unroll
    for (int u = 0; u < NPB / 2; ++u) {
        int n = g * (NPB / 2) + u;
        int node = n0 + n;
        float a = 0.f, f = 0.f;
        if (node < N) {
            a = agg[(size_t)node * MODEL_D + j];
            f = feat[(size_t)node * MODEL_D + j];
        }
        xs[n][j] = a;
        xs[n][MODEL_D + j] = f;
    }
    __syncthreads();

    const int nbase = g * (NPB / 2);
    float acc[NPB / 2];

    // ---- layer 1: [2D] -> [D], ReLU ----
    {
        float bias = b1[j];
        #pragma unroll
        for (int n = 0; n < NPB / 2; ++n) acc[n] = bias;
        for (int k = 0; k < 2 * MODEL_D; k += 4) {
            float w0 = W1[(k + 0) * MODEL_D + j];
            float w1 = W1[(k + 1) * MODEL_D + j];
            float w2 = W1[(k + 2) * MODEL_D + j];
            float w3 = W1[(k + 3) * MODEL_D + j];
            #pragma unroll
            for (int n = 0; n < NPB / 2; ++n) {
                float4 x = *reinterpret_cast<const float4*>(&xs[nbase + n][k]);
                acc[n] = fmaf(x.x, w0, acc[n]);
                acc[n] = fmaf(x.y, w1, acc[n]);
                acc[n] = fmaf(x.z, w2, acc[n]);
                acc[n] = fmaf(x.w, w3, acc[n]);
            }
        }
        #pragma unroll
        for (int n = 0; n < NPB / 2; ++n) hs[nbase + n][j] = fmaxf(acc[n], 0.f);
    }
    __syncthreads();

    // ---- layer 2: [D] -> [D], ReLU ----
    {
        float bias = b2[j];
        #pragma unroll
        for (int n = 0; n < NPB / 2; ++n) acc[n] = bias;
        for (int k = 0; k < MODEL_D; k += 4) {
            float w0 = W2[(k + 0) * MODEL_D + j];
            float w1 = W2[(k + 1) * MODEL_D + j];
            float w2 = W2[(k + 2) * MODEL_D + j];
            float w3 = W2[(k + 3) * MODEL_D + j];
            #pragma unroll
            for (int n = 0; n < NPB / 2; ++n) {
                float4 x = *reinterpret_cast<const float4*>(&hs[nbase + n][k]);
                acc[n] = fmaf(x.x, w0, acc[n]);
                acc[n] = fmaf(x.y, w1, acc[n]);
                acc[n] = fmaf(x.z, w2, acc[n]);
                acc[n] = fmaf(x.w, w3, acc[n]);
            }
        }
    }
    __syncthreads();
    #pragma unroll
    for (int n = 0; n < NPB / 2; ++n) xs[nbase + n][j] = fmaxf(acc[n], 0.f);
    __syncthreads();

    // ---- layer 3: [D] -> [D], no activation ----
    {
        float bias = b3[j];
        #pragma unroll
        for (int n = 0; n < NPB / 2; ++n) acc[n] = bias;
        for (int k = 0; k < MODEL_D; k += 4) {
            float w0 = W3[(k + 0) * MODEL_D + j];
            float w1 = W3[(k + 1) * MODEL_D + j];
            float w2 = W3[(k + 2) * MODEL_D + j];
            float w3 = W3[(k + 3) * MODEL_D + j];
            #pragma unroll
            for (int n = 0; n < NPB / 2; ++n) {
                float4 x = *reinterpret_cast<const float4*>(&xs[nbase + n][k]);
                acc[n] = fmaf(x.x, w0, acc[n]);
                acc[n] = fmaf(x.y, w1, acc[n]);
                acc[n] = fmaf(x.z, w2, acc[n]);
                acc[n] = fmaf(x.w, w3, acc[n]);
            }
        }
        #pragma unroll
        for (int n = 0; n < NPB / 2; ++n) {
            int node = n0 + nbase + n;
            if (node < N) out[(size_t)node * MODEL_D + j] = acc[n];
        }
    }
}

extern "C" void kernel_launch(void* const* d_in, const int* in_sizes, int n_in,
                              void* d_out, int out_size, void* d_ws, size_t ws_size,
                              hipStream_t stream) {
    const float* feat = (const float*)d_in[0];
    const int*   src  = (const int*)d_in[1];
    const int*   dst  = (const int*)d_in[2];
    const float* W1   = (const float*)d_in[3];
    const float* b1   = (const float*)d_in[4];
    const float* W2   = (const float*)d_in[5];
    const float* b2   = (const float*)d_in[6];
    const float* W3   = (const float*)d_in[7];
    const float* b3   = (const float*)d_in[8];
    float* out = (float*)d_out;

    const int N = in_sizes[0] / MODEL_D;
    const int E = in_sizes[1];

    // ws layout: deg[N] | offsets[N] | cursor[N] | srcSorted[E] | agg[N*D]
    int* deg       = (int*)d_ws;
    int* offsets   = deg + N;
    int* cursor    = offsets + N;
    int* srcSorted = cursor + N;
    float* agg     = (float*)(srcSorted + E);

    hipMemsetAsync(deg, 0, (size_t)N * sizeof(int), stream);

    int gE = min((E + 1023) / 1024, 1024);
    hist_kernel<<<gE, 1024, 0, stream>>>(dst, deg, E);
    scan_kernel<<<1, 1024, 0, stream>>>(deg, offsets, cursor, N);
    fill_kernel<<<gE, 1024, 0, stream>>>(src, dst, cursor, srcSorted, E);

    int ablocks = (N * MODEL_D + 255) / 256;
    agg_kernel<<<ablocks, 256, 0, stream>>>(feat, offsets, deg, srcSorted, agg, N);

    int mblocks = (N + NPB - 1) / NPB;
    mlp_kernel<<<mblocks, MLP_THREADS, 0, stream>>>(
        agg, feat, W1, b1, W2, b2, W3, b3, out, N);
}